// Round 9
// baseline (501.847 us; speedup 1.0000x reference)
//
#include <hip/hip_runtime.h>
#include <hip/hip_bf16.h>
#include <stdint.h>

// Problem constants (from reference)
#define N_NODES 100000
#define N_EDGES 1600000
#define D_NODE  32
#define D_EDGE  16
#define D_IN    48   // D_NODE + D_EDGE
#define D_HID   64
#define D_OUT   32

// ---------------- workspace layout (bytes) ----------------
#define NFLAGS_OFF  ((size_t)0)          // 2 ints: {is_bf16, is_int64}
#define NB1_OFF     ((size_t)64)         // fp32 [64]
#define NB2_OFF     ((size_t)320)        // fp32 [32]
#define W1BF_OFF    ((size_t)1024)       // bf16 [n=64][k=64] n-major, k>=48 zero
#define W2BF_OFF    ((size_t)9216)       // bf16 [n=32][k=64] n-major
#define XB_OFF      ((size_t)16384)      // bf16 x table [N_NODES][32] = 6.4 MB
#define COUNTS_OFF  ((size_t)6416384)    // int [N_NODES]
#define OFFS_OFF    ((size_t)6816384)    // int [N_NODES+1]
#define BLKSUM_OFF  ((size_t)7216640)    // int [512]
#define RANK_OFF    ((size_t)7218688)    // int [N_EDGES] 6.4 MB
#define SRCS_OFF    ((size_t)13618688)   // int [N_EDGES] sorted src, 6.4 MB
#define EASORT_OFF  ((size_t)20018688)   // bf16 [N_EDGES][16] sorted ea, 51.2 MB

#define SCAN_NB  391    // ceil(100000/256)
#define PREP_NB  1563   // ceil(3,200,000/2048) elem-conversion blocks
#define EDGE_NB  6250   // N_EDGES/256
#define FUSED_NB 25000  // N_NODES/4 (4 waves/block, wave = 1 node)

typedef __attribute__((ext_vector_type(8))) short bf16x8;   // 8 bf16 = 4 VGPRs
typedef __attribute__((ext_vector_type(4))) float f32x4;

__device__ inline float bf2f(unsigned int u16) {
    return __uint_as_float(u16 << 16);
}
__device__ inline unsigned short f2bf_rne(float f) {
    unsigned int x = __float_as_uint(f);
    unsigned int r = (x + 0x7FFFu + ((x >> 16) & 1u)) >> 16;
    return (unsigned short)r;
}
// packed RNE fp32x2 -> bf16x2 (v_cvt_pk_bf16_f32 on gfx950)
__device__ inline unsigned int pk_bf2(float a, float b) {
    float2 f; f.x = a; f.y = b;
    __hip_bfloat162 h = __float22bfloat162_rn(f);
    return *reinterpret_cast<unsigned int*>(&h);
}
__device__ inline float ld_f(const void* p, int i, int isbf) {
    if (isbf) return bf2f(((const unsigned short*)p)[i]);
    return ((const float*)p)[i];
}
__device__ inline uint4 pack8(float4 v0, float4 v1) {
    uint4 r;
    r.x = pk_bf2(v0.x, v0.y); r.y = pk_bf2(v0.z, v0.w);
    r.z = pk_bf2(v1.x, v1.y); r.w = pk_bf2(v1.z, v1.w);
    return r;
}

// ---------------------------------------------------------------------------
// Prep (grid-wide, PREP_NB blocks): every block locally detects dtypes (wave-0
// ballot on the same 64 halfwords -> no cross-block dependency), zeroes its
// counts slice, converts its x slice into the bf16 table. Block 0 additionally
// publishes flags and builds bf16 n-major weights + fp32 biases.
// ---------------------------------------------------------------------------
__global__ __launch_bounds__(256) void prep_kernel(
        const void* __restrict__ xq, const void* __restrict__ idxq,
        const void* __restrict__ W1q, const void* __restrict__ b1q,
        const void* __restrict__ W2q, const void* __restrict__ b2q,
        char* __restrict__ ws) {
    const int t = threadIdx.x;
    __shared__ int s_isbf;
    if (t < 64) {   // per-block wave-0 dtype detection (L2-broadcast reads)
        unsigned short u = ((const unsigned short*)xq)[t];
        unsigned long long mb = __ballot(((u >> 7) & 0xFF) >= 140);
        if (t == 0) s_isbf = (mb == 0ULL);
        if (blockIdx.x == 0) {
            int wodd = ((const int*)idxq)[2 * t + 1];
            unsigned long long mi = __ballot(wodd != 0);
            if (t == 0) {
                int* flags = (int*)(ws + NFLAGS_OFF);
                flags[0] = (mb == 0ULL);   // no big exponents -> genuine bf16
                flags[1] = (mi == 0ULL);   // all odd words zero -> int64
            }
        }
    }
    __syncthreads();
    const int isbf = s_isbf;

    // zero counts slice (blocks 0..390 cover it)
    const int i0 = blockIdx.x * 256 + t;
    if (i0 < N_NODES) ((int*)(ws + COUNTS_OFF))[i0] = 0;

    // convert x -> bf16 table, 8 elems/thread
    const int g8 = i0 * 8;
    if (g8 < N_NODES * D_NODE) {
        unsigned short* xb = (unsigned short*)(ws + XB_OFF);
        if (isbf) {
            *(uint4*)(xb + g8) = *(const uint4*)((const unsigned short*)xq + g8);
        } else {
            const float4* xp = (const float4*)((const float*)xq + g8);
            *(uint4*)(xb + g8) = pack8(xp[0], xp[1]);
        }
    }

    if (blockIdx.x != 0) return;
    float* b1 = (float*)(ws + NB1_OFF);
    float* b2 = (float*)(ws + NB2_OFF);
    unsigned short* w1b = (unsigned short*)(ws + W1BF_OFF);
    unsigned short* w2b = (unsigned short*)(ws + W2BF_OFF);

    if (t < D_HID) b1[t] = ld_f(b1q, t, isbf);
    if (t < D_OUT) b2[t] = ld_f(b2q, t, isbf);

    // w1b[n][k] = W1[k][n] (k>=48 zero);  w2b[n][k] = W2[k][n]
    for (int i = t; i < D_HID * 64; i += 256) {
        int n = i >> 6, k = i & 63;
        float v = (k < D_IN) ? ld_f(W1q, k * D_HID + n, isbf) : 0.0f;
        w1b[i] = f2bf_rne(v);
    }
    for (int i = t; i < D_OUT * 64; i += 256) {
        int n = i >> 6, k = i & 63;
        w2b[i] = f2bf_rne(ld_f(W2q, k * D_OUT + n, isbf));
    }
}

// ---------------------------------------------------------------------------
// Histogram + per-edge rank (atomic return value); coalesced 4B/edge write.
// ---------------------------------------------------------------------------
__global__ __launch_bounds__(256) void hist_kernel(const void* __restrict__ idxq,
                                                   char* __restrict__ ws,
                                                   int* __restrict__ rankb) {
    const int is64 = ((const int*)(ws + NFLAGS_OFF))[1];
    const int e = blockIdx.x * 256 + threadIdx.x;
    int dst;
    if (is64) dst = (int)((const long long*)idxq)[e];
    else      dst = ((const int*)idxq)[e];
    rankb[e] = atomicAdd((int*)(ws + COUNTS_OFF) + dst, 1);
}

__global__ __launch_bounds__(256) void scan_block_kernel(char* __restrict__ ws) {
    __shared__ int s[256];
    const int* counts = (const int*)(ws + COUNTS_OFF);
    int* offs   = (int*)(ws + OFFS_OFF);
    int* blksum = (int*)(ws + BLKSUM_OFF);
    const int t = threadIdx.x;
    const int i = blockIdx.x * 256 + t;
    int v = (i < N_NODES) ? counts[i] : 0;
    s[t] = v;
    __syncthreads();
    for (int d = 1; d < 256; d <<= 1) {
        int a = (t >= d) ? s[t - d] : 0;
        __syncthreads();
        s[t] += a;
        __syncthreads();
    }
    if (i < N_NODES) offs[i] = s[t] - v;      // local exclusive
    if (t == 255) blksum[blockIdx.x] = s[255];
}

// scan_add with built-in top-level prefix: block b sums blksum[0..b-1] itself.
__global__ __launch_bounds__(256) void scan_add_kernel(char* __restrict__ ws) {
    __shared__ int s[256];
    int* offs = (int*)(ws + OFFS_OFF);
    const int* blksum = (const int*)(ws + BLKSUM_OFF);
    const int t = threadIdx.x;
    const int b = blockIdx.x;
    int acc = 0;
    for (int j = t; j < b; j += 256) acc += blksum[j];
    s[t] = acc;
    __syncthreads();
    for (int d = 128; d > 0; d >>= 1) {
        if (t < d) s[t] += s[t + d];
        __syncthreads();
    }
    const int prefix = s[0];
    const int i = b * 256 + t;
    if (i < N_NODES) offs[i] += prefix;
    if (i == 0) offs[N_NODES] = N_EDGES;
}

// ---------------------------------------------------------------------------
// Permute: scatter each edge's bf16-packed ea row (32B) and src (4B) into
// destination-sorted position pos = offs[dst] + rank[e]. Coalesced reads;
// this is the pipeline's single unavoidable scatter.
// ---------------------------------------------------------------------------
__global__ __launch_bounds__(256) void permute_kernel(
        const void* __restrict__ idxq, const void* __restrict__ eaq,
        const char* __restrict__ wsro,
        const int* __restrict__ rankb,
        int* __restrict__ srcsort, unsigned short* __restrict__ easort) {
    const int isbf = ((const int*)(wsro + NFLAGS_OFF))[0];
    const int is64 = ((const int*)(wsro + NFLAGS_OFF))[1];
    const int* offs = (const int*)(wsro + OFFS_OFF);
    const int e = blockIdx.x * 256 + threadIdx.x;
    int dst, src;
    if (is64) {
        const long long* ip = (const long long*)idxq;
        dst = (int)ip[e];
        src = (int)ip[N_EDGES + e];
    } else {
        const int* ip = (const int*)idxq;
        dst = ip[e];
        src = ip[N_EDGES + e];
    }
    const int pos = offs[dst] + rankb[e];

    uint4 p0, p1;
    if (isbf) {
        const uint4* ap = (const uint4*)((const unsigned short*)eaq + (size_t)e * D_EDGE);
        p0 = ap[0]; p1 = ap[1];
    } else {
        const float4* ap = (const float4*)((const float*)eaq + (size_t)e * D_EDGE);
        p0 = pack8(ap[0], ap[1]);
        p1 = pack8(ap[2], ap[3]);
    }
    uint4* row = (uint4*)(easort + (size_t)pos * D_EDGE);
    row[0] = p0;
    row[1] = p1;
    srcsort[pos] = src;
}

// ---------------------------------------------------------------------------
// FUSED node kernel: one wave per node (4 waves/block). Per 16-edge tile of
// the node's sorted slot range [lo,hi):
//   A0 = xb[src] bf16 row (16B/lane gather, 6.4MB L2-resident table)
//   A1 = easort[slot] bf16 row ((q&1): lanes q>=2 feed k=48..63 whose W1
//        rows are ZERO -> garbage multiplies to exactly 0)
//   layer1 (c=b1) -> relu -> hbuf (stride-72, per-wave) -> A-layout reads
//   layer2 (c=0) -> masked row-sum into per-lane fp32 accumulators
// After tiles: shfl_xor over the quad bits (16,32) -> 32 column sums; add
// deg*b2; write out[n] directly. No atomics, no message buffer, no reduce
// kernel. Padded rows masked; deg==0 correctly writes 0. fp32 accumulation
// throughout layer2->output (better than the old bf16 msg round-trip).
// ---------------------------------------------------------------------------
__global__ __launch_bounds__(256) void fused_node_kernel(
        const char* __restrict__ wsro,
        const int* __restrict__ srcsort,
        const unsigned short* __restrict__ easort,
        void* __restrict__ out) {
    const int isbf = ((const int*)(wsro + NFLAGS_OFF))[0];

    __shared__ __align__(16) unsigned short hbuf[4][16][72];

    const int w   = threadIdx.x >> 6;
    const int l   = threadIdx.x & 63;
    const int m16 = l & 15;
    const int q   = l >> 4;

    const unsigned short* w1b = (const unsigned short*)(wsro + W1BF_OFF);
    const unsigned short* w2b = (const unsigned short*)(wsro + W2BF_OFF);
    const unsigned short* xb  = (const unsigned short*)(wsro + XB_OFF);
    const float* b1 = (const float*)(wsro + NB1_OFF);
    const float* b2 = (const float*)(wsro + NB2_OFF);
    const int* offs = (const int*)(wsro + OFFS_OFF);

    // B-fragments (L1-hot, same addresses for every wave)
    bf16x8 w1f[4][2], w2f[2][2];
#pragma unroll
    for (int t = 0; t < 4; ++t)
#pragma unroll
        for (int c = 0; c < 2; ++c)
            w1f[t][c] = *(const bf16x8*)(w1b + ((t * 16 + m16) * 64 + c * 32 + q * 8));
#pragma unroll
    for (int t = 0; t < 2; ++t)
#pragma unroll
        for (int c = 0; c < 2; ++c)
            w2f[t][c] = *(const bf16x8*)(w2b + ((t * 16 + m16) * 64 + c * 32 + q * 8));

    const int n = blockIdx.x * 4 + w;
    const int lo = offs[n], hi = offs[n + 1];
    const int deg = hi - lo;

    const float b1v[4] = { b1[m16], b1[16 + m16], b1[32 + m16], b1[48 + m16] };

    f32x4 acc0, acc1;   // per-lane masked row-sums for cols m16 / 16+m16
    acc0[0]=acc0[1]=acc0[2]=acc0[3]=0.f;
    acc1[0]=acc1[1]=acc1[2]=acc1[3]=0.f;
    float s0 = 0.f, s1 = 0.f;

    for (int base = lo; base < hi; base += 16) {
        const int slot = base + m16;
        const int sidx = (slot < N_EDGES) ? slot : (N_EDGES - 1);   // clamp pad reads
        const int src  = srcsort[sidx];

        bf16x8 a0 = *(const bf16x8*)(xb + (size_t)src * D_NODE + q * 8);
        bf16x8 a1 = *(const bf16x8*)(easort + (size_t)sidx * D_EDGE + (q & 1) * 8);

        // ---- layer 1: relu([16x48(pad64)] @ [48x64] + b1) -> hbuf ----
#pragma unroll
        for (int t = 0; t < 4; ++t) {
            f32x4 c;
            c[0] = c[1] = c[2] = c[3] = b1v[t];
            c = __builtin_amdgcn_mfma_f32_16x16x32_bf16(a0, w1f[t][0], c, 0, 0, 0);
            c = __builtin_amdgcn_mfma_f32_16x16x32_bf16(a1, w1f[t][1], c, 0, 0, 0);
            unsigned int u0 = pk_bf2(fmaxf(c[0], 0.0f), fmaxf(c[1], 0.0f));
            unsigned int u1 = pk_bf2(fmaxf(c[2], 0.0f), fmaxf(c[3], 0.0f));
            hbuf[w][q * 4 + 0][t * 16 + m16] = (unsigned short)u0;
            hbuf[w][q * 4 + 1][t * 16 + m16] = (unsigned short)(u0 >> 16);
            hbuf[w][q * 4 + 2][t * 16 + m16] = (unsigned short)u1;
            hbuf[w][q * 4 + 3][t * 16 + m16] = (unsigned short)(u1 >> 16);
        }

        // ---- layer 2 (c=0), masked row accumulation ----
        bf16x8 a20 = *(const bf16x8*)(&hbuf[w][m16][q * 8]);
        bf16x8 a21 = *(const bf16x8*)(&hbuf[w][m16][32 + q * 8]);
        f32x4 c0, c1;
        c0[0]=c0[1]=c0[2]=c0[3]=0.f;
        c1[0]=c1[1]=c1[2]=c1[3]=0.f;
        c0 = __builtin_amdgcn_mfma_f32_16x16x32_bf16(a20, w2f[0][0], c0, 0, 0, 0);
        c0 = __builtin_amdgcn_mfma_f32_16x16x32_bf16(a21, w2f[0][1], c0, 0, 0, 0);
        c1 = __builtin_amdgcn_mfma_f32_16x16x32_bf16(a20, w2f[1][0], c1, 0, 0, 0);
        c1 = __builtin_amdgcn_mfma_f32_16x16x32_bf16(a21, w2f[1][1], c1, 0, 0, 0);

        const int rem = hi - base;   // >=16 for full tiles
        if (rem >= 16) {
#pragma unroll
            for (int r = 0; r < 4; ++r) { acc0[r] += c0[r]; acc1[r] += c1[r]; }
        } else {
#pragma unroll
            for (int r = 0; r < 4; ++r) {
                if (q * 4 + r < rem) { acc0[r] += c0[r]; acc1[r] += c1[r]; }
            }
        }
    }

    s0 = acc0[0] + acc0[1] + acc0[2] + acc0[3];
    s1 = acc1[0] + acc1[1] + acc1[2] + acc1[3];
    // reduce across the 4 quads (lane bits 4,5)
    s0 += __shfl_xor(s0, 16, 64);  s1 += __shfl_xor(s1, 16, 64);
    s0 += __shfl_xor(s0, 32, 64);  s1 += __shfl_xor(s1, 32, 64);

    s0 += (float)deg * b2[m16];
    s1 += (float)deg * b2[16 + m16];

    if (isbf) {
        unsigned short* o16 = (unsigned short*)out + (size_t)n * D_OUT;
        if (q == 0) o16[m16]      = f2bf_rne(s0);
        else if (q == 1) o16[16 + m16] = f2bf_rne(s1);
    } else {
        float* of = (float*)out + (size_t)n * D_OUT;
        if (q == 0) of[m16]      = s0;
        else if (q == 1) of[16 + m16] = s1;
    }
}

extern "C" void kernel_launch(void* const* d_in, const int* in_sizes, int n_in,
                              void* d_out, int out_size, void* d_ws, size_t ws_size,
                              hipStream_t stream) {
    const void* x   = d_in[0];
    const void* idx = d_in[1];
    const void* ea  = d_in[2];
    const void* W1  = d_in[3];
    const void* b1  = d_in[4];
    const void* W2  = d_in[5];
    const void* b2  = d_in[6];
    char* ws = (char*)d_ws;

    hipLaunchKernelGGL(prep_kernel, dim3(PREP_NB), dim3(256), 0, stream,
                       x, idx, W1, b1, W2, b2, ws);

    hipLaunchKernelGGL(hist_kernel, dim3(EDGE_NB), dim3(256), 0, stream,
                       idx, ws, (int*)(ws + RANK_OFF));

    hipLaunchKernelGGL(scan_block_kernel, dim3(SCAN_NB), dim3(256), 0, stream, ws);
    hipLaunchKernelGGL(scan_add_kernel,   dim3(SCAN_NB), dim3(256), 0, stream, ws);

    hipLaunchKernelGGL(permute_kernel, dim3(EDGE_NB), dim3(256), 0, stream,
                       idx, ea, (const char*)ws, (const int*)(ws + RANK_OFF),
                       (int*)(ws + SRCS_OFF), (unsigned short*)(ws + EASORT_OFF));

    hipLaunchKernelGGL(fused_node_kernel, dim3(FUSED_NB), dim3(256), 0, stream,
                       (const char*)ws, (const int*)(ws + SRCS_OFF),
                       (const unsigned short*)(ws + EASORT_OFF), d_out);
}